// Round 1
// baseline (238.137 us; speedup 1.0000x reference)
//
#include <hip/hip_runtime.h>
#include <math.h>

#define BATCH 32
#define N 128
#define H 100
#define EF 4
// rows = BATCH*N = 4096

// K1: hw[row,h] = sum_k hidden[row,k] * Ww[k,h]
__global__ __launch_bounds__(128) void k_hw(const float* __restrict__ hidden,
                                            const float* __restrict__ Ww,
                                            float* __restrict__ hw) {
    const int row = blockIdx.x;
    const int t = threadIdx.x;
    __shared__ float hid[H];
    if (t < H) hid[t] = hidden[row * H + t];
    __syncthreads();
    if (t < H) {
        float acc = 0.f;
#pragma unroll 4
        for (int k = 0; k < H; ++k) acc = fmaf(hid[k], Ww[k * H + t], acc);
        hw[row * H + t] = acc;
    }
}

// K2: per (b,v) row — fused hv projection, message accumulation over w,
//     and tanh update through Wu. In-place hidden update (only own row read).
__global__ __launch_bounds__(128) void k_msg_upd(const float* __restrict__ edges,
                                                 const float* __restrict__ Wv,
                                                 const float* __restrict__ We,
                                                 const float* __restrict__ Wu,
                                                 const float* __restrict__ hw,
                                                 float* __restrict__ hidden,
                                                 float* __restrict__ node_mask) {
    const int row = blockIdx.x;           // b*N + v
    const int b = row >> 7;               // N = 128
    const int t = threadIdx.x;

    __shared__ float hid[H];
    __shared__ float4 erow[N];
    __shared__ float asum[N];
    __shared__ float msg[H];
    __shared__ float nodesum;

    if (t < H) hid[t] = hidden[row * H + t];
    {   // stage this row's 128 edges (float4 each) + per-edge adjacency sums
        const float4* e4 = (const float4*)(edges + (size_t)row * N * EF);
        float4 e = e4[t];
        erow[t] = e;
        asum[t] = ((e.x + e.y) + e.z) + e.w;
    }
    __syncthreads();

    if (t == 0) {
        float s = 0.f;
        for (int w = 0; w < N; ++w) s += asum[w];
        nodesum = s;
        node_mask[row] = (s != 0.f) ? 1.f : 0.f;
    }

    if (t < H) {
        // hv for this row (only consumed by this block)
        float hv = 0.f;
#pragma unroll 4
        for (int k = 0; k < H; ++k) hv = fmaf(hid[k], Wv[k * H + t], hv);

        const float we0 = We[t];
        const float we1 = We[H + t];
        const float we2 = We[2 * H + t];
        const float we3 = We[3 * H + t];

        const float* hwb = hw + (size_t)b * N * H + t;
        float acc = 0.f;
#pragma unroll 4
        for (int w = 0; w < N; ++w) {
            const float4 e = erow[w];
            float pre = hv + hwb[w * H];
            pre = fmaf(e.x, we0, pre);
            pre = fmaf(e.y, we1, pre);
            pre = fmaf(e.z, we2, pre);
            pre = fmaf(e.w, we3, pre);
            acc += (asum[w] != 0.f) ? fmaxf(pre, 0.f) : 0.f;
        }
        msg[t] = acc;
    }
    __syncthreads();   // msg + nodesum visible

    if (t < H) {
        float u = 0.f;
#pragma unroll 4
        for (int k = 0; k < H; ++k) u = fmaf(hid[k], Wu[k * H + t], u);
#pragma unroll 4
        for (int k = 0; k < H; ++k) u = fmaf(msg[k], Wu[(H + k) * H + t], u);
        const float newh = (nodesum != 0.f) ? tanhf(u) : hid[t];
        hidden[row * H + t] = newh;
    }
}

// K3: readout — graph_terms row then masked atomic accumulate into out[b,:]
__global__ __launch_bounds__(128) void k_readout(const float* __restrict__ hidden,
                                                 const float* __restrict__ nodes,
                                                 const float* __restrict__ Wr,
                                                 const float* __restrict__ node_mask,
                                                 float* __restrict__ out) {
    const int row = blockIdx.x;
    const int b = row >> 7;
    const int t = threadIdx.x;
    __shared__ float hid[H];
    __shared__ float nod[H];
    if (t < H) {
        hid[t] = hidden[row * H + t];
        nod[t] = nodes[row * H + t];
    }
    __syncthreads();
    if (node_mask[row] == 0.f) return;   // uniform; no barriers after this
    if (t < H) {
        float u = 0.f;
#pragma unroll 4
        for (int k = 0; k < H; ++k) u = fmaf(hid[k], Wr[k * H + t], u);
#pragma unroll 4
        for (int k = 0; k < H; ++k) u = fmaf(nod[k], Wr[(H + k) * H + t], u);
        u = fmaxf(u, 0.f);
        atomicAdd(&out[b * H + t], u);
    }
}

extern "C" void kernel_launch(void* const* d_in, const int* in_sizes, int n_in,
                              void* d_out, int out_size, void* d_ws, size_t ws_size,
                              hipStream_t stream) {
    const float* nodes = (const float*)d_in[0];  // [B,N,H]
    const float* edges = (const float*)d_in[1];  // [B,N,N,4]
    const float* Wv    = (const float*)d_in[2];  // [H,H]
    const float* Ww    = (const float*)d_in[3];  // [H,H]
    const float* We    = (const float*)d_in[4];  // [4,H]
    const float* Wu    = (const float*)d_in[5];  // [2H,H]
    const float* Wr    = (const float*)d_in[6];  // [2H,H]
    float* out = (float*)d_out;                  // [B,H] fp32

    const int rows = BATCH * N;                  // 4096
    float* hidden = (float*)d_ws;                // rows*H
    float* hwbuf  = hidden + (size_t)rows * H;   // rows*H
    float* nmask  = hwbuf + (size_t)rows * H;    // rows

    // hidden <- nodes (d2d async: graph-capture safe)
    hipMemcpyAsync(hidden, nodes, (size_t)rows * H * sizeof(float),
                   hipMemcpyDeviceToDevice, stream);
    // out is poisoned 0xAA before every timed call — zero it
    hipMemsetAsync(d_out, 0, (size_t)out_size * sizeof(float), stream);

    for (int p = 0; p < 3; ++p) {
        k_hw<<<rows, 128, 0, stream>>>(hidden, Ww, hwbuf);
        k_msg_upd<<<rows, 128, 0, stream>>>(edges, Wv, We, Wu, hwbuf, hidden, nmask);
    }
    k_readout<<<rows, 128, 0, stream>>>(hidden, nodes, Wr, nmask, out);
}